// Round 12
// baseline (494.718 us; speedup 1.0000x reference)
//
#include <hip/hip_runtime.h>
#include <hip/hip_bf16.h>
#include <cstdint>

#define EPS_BN 1e-5f

typedef __attribute__((ext_vector_type(8)))  short bf16x8;   // 8 bf16 = 4 VGPRs
typedef __attribute__((ext_vector_type(16))) float f32x16;   // MFMA 32x32 acc
typedef __attribute__((ext_vector_type(4)))  unsigned short u16x4;

#define MFMA32(a, b, c) __builtin_amdgcn_mfma_f32_32x32x16_bf16(a, b, c, 0, 0, 0)

// async global->LDS, 16B/lane: per-lane GLOBAL src, LDS dst = uniform base + lane*16
#define GLOAD_LDS16(gsrc, ldst) \
    __builtin_amdgcn_global_load_lds((const __attribute__((address_space(1))) void*)(gsrc), \
                                     (__attribute__((address_space(3))) void*)(ldst), 16, 0, 0)

// ---------------------------------------------------------------------------
// invd (stage-1): plain transposed inverted map invT[k*n_down + s] = g.
// ---------------------------------------------------------------------------
__global__ void build_inv(const int* __restrict__ gather, const int* __restrict__ scatter,
                          long total, int m, int* __restrict__ invT, int n_down) {
    long i = (long)blockIdx.x * blockDim.x + threadIdx.x;
    if (i >= total) return;
    int s = scatter[i];
    if (s < n_down) {
        int k = (int)(i / m);
        invT[(long)k * n_down + s] = gather[i];
    }
}

// ---------------------------------------------------------------------------
// invP (stage-2): PERMUTED inverted map in 128-row blocks. Row r of a block
// is stored at pos(r) = (r>>5)*32 + (r&7)*4 + ((r>>3)&3), so a wave reads its
// 128 stage indices with FOUR coalesced dwordx4 loads already in
// stage-instruction layout (load q, lane-group ro -> instrs 4q..4q+3).
// ---------------------------------------------------------------------------
__global__ void build_invP(const int* __restrict__ gather, const int* __restrict__ scatter,
                           long total, int m, int* __restrict__ invP, int n_down, int nb128) {
    long i = (long)blockIdx.x * blockDim.x + threadIdx.x;
    if (i >= total) return;
    int s = scatter[i];
    if (s < n_down) {
        int k = (int)(i / m);
        int r = s & 127;
        int pos = ((r >> 5) << 5) + ((r & 7) << 2) + ((r >> 3) & 3);
        invP[(size_t)k * nb128 + ((size_t)(s >> 7) << 7) + pos] = gather[i];
    }
}

// feat f32[n_in][32] -> bf16 [n_in+1][32] (pad row zero); also zero ybf pad row.
__global__ void fcvt(const float* __restrict__ f, unsigned short* __restrict__ fb,
                     unsigned short* __restrict__ ybf_pad, long n_in) {
    long t = (long)blockIdx.x * blockDim.x + threadIdx.x;
    long e = t * 4;
    long total = n_in * 32;
    if (e < total) {
        float4 v = *(const float4*)(f + e);
        u16x4 o;
        __hip_bfloat16 h;
        h = __float2bfloat16(v.x); o.x = *(unsigned short*)&h;
        h = __float2bfloat16(v.y); o.y = *(unsigned short*)&h;
        h = __float2bfloat16(v.z); o.z = *(unsigned short*)&h;
        h = __float2bfloat16(v.w); o.w = *(unsigned short*)&h;
        *(u16x4*)(fb + e) = o;
    } else if (e < total + 32) {
        u16x4 z = {0, 0, 0, 0};
        *(u16x4*)(fb + e) = z;
    }
    if (blockIdx.x == 0 && threadIdx.x < 16) {
        u16x4 z = {0, 0, 0, 0};
        ((u16x4*)ybf_pad)[threadIdx.x] = z;
    }
}

// w_ref f32[81][64cin][64cout] -> bf16 wt[k][kq(4)][col(64)][16]: slot
// (col, lhi*8+j) of kq holds w[cin = kq*16+lhi*8+j][col].
__global__ void wcvt_r(const float* __restrict__ w, unsigned short* __restrict__ wt) {
    int e = blockIdx.x * 256 + threadIdx.x;      // 81*4096
    int k = e >> 12, r = e & 4095;
    int cin = ((r >> 10) << 4) + (r & 15);
    int col = (r >> 4) & 63;
    __hip_bfloat16 h = __float2bfloat16(w[(k << 12) + (cin << 6) + col]);
    wt[e] = *(unsigned short*)&h;
}

// w_down f32[16][32cin][64cout] -> bf16 wtd[k][kq(2)][col(64)][16]
__global__ void wcvt_d(const float* __restrict__ w, unsigned short* __restrict__ wt) {
    int e = blockIdx.x * 256 + threadIdx.x;      // 16*2048
    int k = e >> 11, r = e & 2047;
    int cin = ((r >> 10) << 4) + (r & 15);
    int col = (r >> 4) & 63;
    __hip_bfloat16 h = __float2bfloat16(w[(k << 11) + (cin << 6) + col]);
    wt[e] = *(unsigned short*)&h;
}

// ---------------------------------------------------------------------------
// Stage 1: MFMA bf16, K=32, one wave = 32 rows. 91% pad-row gathers (L1-hot).
// ---------------------------------------------------------------------------
__global__ __launch_bounds__(256, 4) void conv_down_mfma(
        const unsigned short* __restrict__ fb, const unsigned short* __restrict__ wtd,
        const int* __restrict__ invd,
        const float* __restrict__ gamma, const float* __restrict__ beta,
        const float* __restrict__ mean, const float* __restrict__ var,
        unsigned short* __restrict__ y, int n_down, int n_in) {
    int  tid  = threadIdx.x;
    int  lane = tid & 63, l31 = lane & 31, lhi = lane >> 5;
    long wv   = ((long)blockIdx.x * 256 + tid) >> 6;
    long o0   = wv * 32;
    if (o0 >= n_down) return;

    int  oA = (int)(o0 + l31 < n_down ? o0 + l31 : n_down - 1);
    const short* ysb = (const short*)fb;

#define LDI_D(k) invd[(size_t)(k) * n_down + oA]
#define GATH_D(dst, g) { \
        const short* p = ysb + (size_t)((g) < 0 ? n_in : (g)) * 32 + lhi * 8; \
        dst[0] = *(const bf16x8*)p; dst[1] = *(const bf16x8*)(p + 16); }

    int g0 = LDI_D(0), gq1 = LDI_D(1), gq2 = LDI_D(2);
    bf16x8 ac[2];
    GATH_D(ac, g0);
    f32x16 acc0 = {}, acc1 = {};
    const short* wp = (const short*)wtd + l31 * 16 + lhi * 8;

    for (int k = 0; k < 16; ++k) {
        int gN = (k < 13) ? LDI_D(k + 3) : -1;
        bf16x8 an[2];
        GATH_D(an, gq1);
        const short* wk = wp + k * 2048;
#pragma unroll
        for (int kq = 0; kq < 2; ++kq) {
            bf16x8 b0 = *(const bf16x8*)(wk + kq * 1024);
            bf16x8 b1 = *(const bf16x8*)(wk + kq * 1024 + 512);
            acc0 = MFMA32(ac[kq], b0, acc0);
            acc1 = MFMA32(ac[kq], b1, acc1);
        }
        ac[0] = an[0]; ac[1] = an[1];
        gq1 = gq2; gq2 = gN;
    }

#pragma unroll
    for (int n = 0; n < 2; ++n) {
        int col = n * 32 + l31;
        float iv = gamma[col] * rsqrtf(var[col] + EPS_BN);
        float bb = beta[col] - mean[col] * iv;
        const f32x16& A = n ? acc1 : acc0;
#pragma unroll
        for (int i = 0; i < 16; ++i) {
            long oo = o0 + (i & 3) + 8 * (i >> 2) + 4 * lhi;
            if (oo < n_down) {
                __hip_bfloat16 h = __float2bfloat16(fmaxf(A[i] * iv + bb, 0.f));
                y[oo * 64 + col] = *(unsigned short*)&h;
            }
        }
    }
#undef LDI_D
#undef GATH_D
}

// ---------------------------------------------------------------------------
// Stage 2: MFMA bf16, wave = 128 rows x 64 cols, 81 regions.
// Sector-rate design (TA ~1x32B/cy/CU, calibrated on R4/R11): sectors/region =
// A 512 + B 256 + idx 16 = 784 per 128 rows (6.1/row vs R4's 8.25).
// A: per-wave DOUBLE-buffered 16KB LDS (full-region lookahead -- the piece
// R9/R10's M=128 lacked); idx: 4 coalesced dwordx4 from permuted table,
// 3 rotating sets (2-region lead); B: single named set, loaded after its
// consuming COMPUTE (1-region lead). Steady vmcnt(20) = drain exactly
// A[k](16)+idx(4)+B[k](8) of 48. 2-wave blocks, 64KB LDS -> 2 blocks/CU
// (4 waves/CU, 1/SIMD: latency hidden by ILP lookahead, not TLP).
// ---------------------------------------------------------------------------
__global__ __launch_bounds__(128, 1) void conv_ref_mfma(
        const unsigned short* __restrict__ ybf, const unsigned short* __restrict__ wt,
        const int* __restrict__ invP,
        const float* __restrict__ gamma, const float* __restrict__ beta,
        const float* __restrict__ mean, const float* __restrict__ var,
        float* __restrict__ out, int n_down, int nb128, int nwg) {
    __shared__ char ldsA[2][2][16384];           // [wave][buf][128 rows x 128B]

    // bijective XCD swizzle (m204)
    int bid = blockIdx.x;
    int q = nwg >> 3, r = nwg & 7;
    int xcd = bid & 7, pos = bid >> 3;
    int swzb = (xcd < r ? xcd * (q + 1) : r * (q + 1) + (xcd - r) * q) + pos;

    const int tid  = threadIdx.x;
    const int lane = tid & 63, l31 = lane & 31, lhi = lane >> 5;
    const int wid  = tid >> 6;
    const long o0  = ((long)swzb * 2 + wid) * 128;
    if (o0 >= n_down) return;                    // barrier-free: early return safe

    const int  ro    = lane >> 3;                // 0..7
    const char* ybase = (const char*)ybf;
    char* ldsw = &ldsA[wid][0][0];
    const int swz = (((lane & 7) ^ ro) << 4);    // staged-source slot swizzle

    // idx base for this wave's 128-row block (o0 is a multiple of 128)
    const char* ibase = (const char*)invP + (size_t)o0 * 4 + (size_t)ro * 16;

    // 4 dwordx4 loads: load q -> instrs 4q..4q+3 (component j&3), lane-group ro
#define IDXP(k, S) { const char* p_ = ibase + (size_t)(k) * ((size_t)nb128 * 4); \
        S##a = *(const int4*)p_;         S##b = *(const int4*)(p_ + 128); \
        S##c = *(const int4*)(p_ + 256); S##d = *(const int4*)(p_ + 384); }

#define GL1(qv, BUF, i) { size_t g_ = (size_t)((qv) < 0 ? n_down : (qv)); \
        GLOAD_LDS16(ybase + g_ * 128 + swz, ldsw + (BUF) * 16384 + (i) * 1024); }

#define STAGE(BUF, S) { \
        GL1(S##a.x, BUF, 0);  GL1(S##a.y, BUF, 1);  GL1(S##a.z, BUF, 2);  GL1(S##a.w, BUF, 3); \
        GL1(S##b.x, BUF, 4);  GL1(S##b.y, BUF, 5);  GL1(S##b.z, BUF, 6);  GL1(S##b.w, BUF, 7); \
        GL1(S##c.x, BUF, 8);  GL1(S##c.y, BUF, 9);  GL1(S##c.z, BUF, 10); GL1(S##c.w, BUF, 11); \
        GL1(S##d.x, BUF, 12); GL1(S##d.y, BUF, 13); GL1(S##d.z, BUF, 14); GL1(S##d.w, BUF, 15); }

#define LDB(k) { \
        const short* wk_ = wp + (size_t)(k) * 4096; \
        _Pragma("unroll") \
        for (int kq = 0; kq < 4; ++kq) { \
            B0[kq] = *(const bf16x8*)(wk_ + kq * 1024); \
            B1[kq] = *(const bf16x8*)(wk_ + kq * 1024 + 512); } }

    const int rsw   = (l31 & 7) << 4;
    const int lhi16 = lhi * 16;

#define COMPUTE(BUF) { \
        const char* la = ldsw + (BUF) * 16384; \
        __builtin_amdgcn_s_setprio(1); \
        _Pragma("unroll") \
        for (int kq = 0; kq < 4; ++kq) { \
            int fo = (kq * 32 + lhi16) ^ rsw; \
            _Pragma("unroll") \
            for (int m = 0; m < 4; ++m) { \
                bf16x8 a_ = *(const bf16x8*)(la + m * 4096 + l31 * 128 + fo); \
                acc[m][0] = MFMA32(a_, B0[kq], acc[m][0]); \
                acc[m][1] = MFMA32(a_, B1[kq], acc[m][1]); } } \
        __builtin_amdgcn_s_setprio(0); }

    // region kk: stage A[kk+1] (set SS = idx[kk+1]), refill SL with idx[kk+3],
    // counted wait, compute CUR, then load B[kk+1] (after its consumer).
#define REGION(CUR, NXT, SS, SL, kk) { \
        STAGE(NXT, SS); \
        IDXP((kk) + 3, SL); \
        asm volatile("s_waitcnt vmcnt(20)" ::: "memory"); \
        __builtin_amdgcn_sched_barrier(0); \
        COMPUTE(CUR); \
        LDB((kk) + 1); }

    f32x16 acc[4][2] = {};
    const short* wp = (const short*)wt + l31 * 16 + lhi * 8;
    bf16x8 B0[4], B1[4];
    int4 S0a, S0b, S0c, S0d, S1a, S1b, S1c, S1d, S2a, S2b, S2c, S2d;

    // prologue: idx[0..2]; A[0] -> buf0; B[0]
    IDXP(0, S0);
    IDXP(1, S1);
    IDXP(2, S2);
    asm volatile("s_waitcnt vmcnt(8)" ::: "memory");   // S0 ready
    __builtin_amdgcn_sched_barrier(0);
    STAGE(0, S0);
    LDB(0);
    // queue: S1(4), S2(4), A0(16), B0(8) = 32 (first wait self-corrects to steady 20)

    // 80 staged regions: 13 x 6 (0..77) + 78, 79; region 80 = compute-only.
    for (int k = 0; k < 78; k += 6) {
        REGION(0, 1, S1, S0, k + 0);
        REGION(1, 0, S2, S1, k + 1);
        REGION(0, 1, S0, S2, k + 2);
        REGION(1, 0, S1, S0, k + 3);
        REGION(0, 1, S2, S1, k + 4);
        REGION(1, 0, S0, S2, k + 5);
    }
    REGION(0, 1, S1, S0, 78);
    REGION(1, 0, S2, S1, 79);
    // region 80: buf0, B[80] already in regs
    asm volatile("s_waitcnt vmcnt(0)" ::: "memory");
    __builtin_amdgcn_sched_barrier(0);
    COMPUTE(0);

    // epilogue: BN + ReLU, f32 out
#pragma unroll
    for (int m = 0; m < 4; ++m)
#pragma unroll
        for (int n = 0; n < 2; ++n) {
            int col = n * 32 + l31;
            float iv = gamma[col] * rsqrtf(var[col] + EPS_BN);
            float bb = beta[col] - mean[col] * iv;
#pragma unroll
            for (int i = 0; i < 16; ++i) {
                long oo = o0 + m * 32 + (i & 3) + 8 * (i >> 2) + 4 * lhi;
                if (oo < n_down)
                    out[oo * 64 + col] = fmaxf(acc[m][n][i] * iv + bb, 0.f);
            }
        }
#undef IDXP
#undef GL1
#undef STAGE
#undef LDB
#undef COMPUTE
#undef REGION
}

extern "C" void kernel_launch(void* const* d_in, const int* in_sizes, int n_args,
                              void* d_out, int out_size, void* d_ws, size_t ws_size,
                              hipStream_t stream) {
    const float* feat    = (const float*)d_in[0];
    const float* w_down  = (const float*)d_in[1];
    const float* gamma_d = (const float*)d_in[2];
    const float* beta_d  = (const float*)d_in[3];
    const float* mean_d  = (const float*)d_in[4];
    const float* var_d   = (const float*)d_in[5];
    const float* w_ref   = (const float*)d_in[6];
    const float* gamma_r = (const float*)d_in[7];
    const float* beta_r  = (const float*)d_in[8];
    const float* mean_r  = (const float*)d_in[9];
    const float* var_r   = (const float*)d_in[10];
    const int*   gather_d  = (const int*)d_in[11];
    const int*   scatter_d = (const int*)d_in[12];
    const int*   gather_r  = (const int*)d_in[13];
    const int*   scatter_r = (const int*)d_in[14];

    int n_in   = in_sizes[0] / 32;
    int md     = in_sizes[11] / 16;
    int mr     = in_sizes[13] / 81;
    int n_down = out_size / 64;
    int nb128  = ((n_down + 127) / 128) * 128;   // permuted-table row stride (ints)

    // ws: ybf[(n_down+1)*64]bf16 | featbf[(n_in+1)*32]bf16 | wt[81*4096]bf16 |
    //     wtd[16*2048]bf16 | invP[84*nb128]i32 | invd[16*n_down]i32 (contig memset)
    char* ws = (char*)d_ws;
    size_t off = 0;
    auto alloc = [&](size_t bytes) { char* p = ws + off; off = (off + bytes + 255) & ~(size_t)255; return p; };
    unsigned short* ybf    = (unsigned short*)alloc((size_t)(n_down + 1) * 64 * 2);
    unsigned short* featbf = (unsigned short*)alloc((size_t)(n_in + 1) * 32 * 2);
    unsigned short* wt     = (unsigned short*)alloc((size_t)81 * 4096 * 2);
    unsigned short* wtd    = (unsigned short*)alloc((size_t)16 * 2048 * 2);
    int* invP = (int*)(ws + off);
    int* invd = invP + (size_t)84 * nb128;

    hipMemsetAsync(invP, 0xFF, ((size_t)84 * nb128 + (size_t)16 * n_down) * sizeof(int), stream);

    long td = 16L * md;
    build_inv<<<(int)((td + 255) / 256), 256, 0, stream>>>(gather_d, scatter_d, td, md, invd, n_down);
    long tr = 81L * mr;
    build_invP<<<(int)((tr + 255) / 256), 256, 0, stream>>>(gather_r, scatter_r, tr, mr, invP, n_down, nb128);

    long ft = ((long)n_in * 32 + 32) / 4;
    fcvt<<<(int)((ft + 255) / 256), 256, 0, stream>>>(feat, featbf, ybf + (size_t)n_down * 64, n_in);
    wcvt_r<<<81 * 4096 / 256, 256, 0, stream>>>(w_ref, wt);
    wcvt_d<<<16 * 2048 / 256, 256, 0, stream>>>(w_down, wtd);

    long wavesD  = ((long)n_down + 31) / 32;
    int  blocksD = (int)((wavesD * 64 + 255) / 256);
    conv_down_mfma<<<blocksD, 256, 0, stream>>>(featbf, wtd, invd,
                                                gamma_d, beta_d, mean_d, var_d,
                                                ybf, n_down, n_in);

    int blocksR = (n_down + 255) / 256;          // 2 waves x 128 rows per block
    conv_ref_mfma<<<blocksR, 128, 0, stream>>>(ybf, wt, invP,
                                               gamma_r, beta_r, mean_r, var_r,
                                               (float*)d_out, n_down, nb128, blocksR);
}